// Round 10
// baseline (495.631 us; speedup 1.0000x reference)
//
#include <hip/hip_runtime.h>
#include <math.h>

#define DEVI __device__ __forceinline__

typedef unsigned short u16;
typedef __attribute__((ext_vector_type(4))) float f32x4;
typedef __attribute__((ext_vector_type(8))) short s16x8;
typedef __attribute__((ext_vector_type(4))) short s16x4;

constexpr int Bc = 4, Sc = 2048, Hc = 1024;
constexpr int NEc = 4, NCc = 16, CDc = 64, ODc = 128;
constexpr float TAUc = 0.5f, TEMPc = 0.07f, EPSc = 1e-5f;

DEVI float gelu_f(float x) { return 0.5f * x * (1.0f + erff(x * 0.7071067811865476f)); }

DEVI float bf2f(u16 u) { union { unsigned int i; float f; } v; v.i = ((unsigned int)u) << 16; return v.f; }
DEVI u16 f2bf(float f) {
  union { float f; unsigned int i; } v; v.f = f;
  unsigned int u = v.i;
  unsigned int r = (u + 0x7fffu + ((u >> 16) & 1u)) >> 16;
  return (u16)r;
}

DEVI float wred_sum(float v) {
  #pragma unroll
  for (int o = 32; o > 0; o >>= 1) v += __shfl_down(v, o);
  return v;
}
DEVI float wred_max(float v) {
  #pragma unroll
  for (int o = 32; o > 0; o >>= 1) v = fmaxf(v, __shfl_down(v, o));
  return v;
}

DEVI void gload16(const void* g, void* l) {
  __builtin_amdgcn_global_load_lds((const __attribute__((address_space(1))) void*)g,
                                   (__attribute__((address_space(3))) void*)l, 16, 0, 0);
}

// ---------------------------------------------------------------------------
// bf16 GEMM, C = act(scale*(A @ Bt^T) + bias) (+ residual), 128x128 tile,
// BK=64, T2 XOR-swizzled LDS (linear gload_lds dest + XOR'd global source
// chunk + XOR'd ds_read slot). Coalesced LDS-staged epilogue.
// Tile order: XCD chunk (blockIdx%8) -> column-major band within the chunk's
// tm-rows, so co-resident blocks per XCD touch ~rows A-panels + ~12 B-panels
// (~5 MB ~ L2) instead of all-tn row-major (10 MB, B thrash -> round-9
// FFN1 FETCH=100MB vs 24MB ideal).
// EPI bits: 1=bias, 2=gelu, 4=residual add, 8=transposed store.
// NOTE (rounds 5-7): 256x256 8-phase "gemm8" compiled to VGPR=128 + full acc
// spill regardless of launch_bounds/waves_per_eu attrs -> abandoned.
// ---------------------------------------------------------------------------
template<int EPI>
__global__ __launch_bounds__(256, 3) void gemm_bt(
    const u16* __restrict__ A, long sAz, int lda,
    const u16* __restrict__ Bt, long sBz, int ldb,
    u16* __restrict__ C, long sCz, int ldc,
    const float* __restrict__ bias,
    const u16* __restrict__ resid, long sRz,
    float scale, int M, int N, int K)
{
  const int bz = blockIdx.z;
  A += (long)bz * sAz; Bt += (long)bz * sBz; C += (long)bz * sCz;
  if (EPI & 4) resid += (long)bz * sRz;

  const int nTn = N >> 7;
  int tm, tn;
  {
    const int nwg = gridDim.x;
    int bid = blockIdx.x;
    if ((nwg & 7) == 0 && ((nwg >> 3) % nTn) == 0) {
      // banded col-major within XCD chunk
      const int rows = (nwg >> 3) / nTn;      // tm-rows per chunk
      const int x = bid & 7, local = bid >> 3;
      tm = x * rows + (local % rows);
      tn = local / rows;
    } else {
      if ((nwg & 7) == 0) bid = ((bid & 7) * (nwg >> 3)) + (bid >> 3);
      tm = bid / nTn; tn = bid % nTn;
    }
  }
  const int tid = threadIdx.x;
  const int wid = tid >> 6, lane = tid & 63;
  const int wr = wid >> 1, wc = wid & 1;
  const int l15 = lane & 15, l4 = lane >> 4;

  __shared__ u16 smem[16384];         // 32 KB: As[128][64] + Bs[128][64]
  u16* As = smem;
  u16* Bs = smem + 8192;

  f32x4 acc[4][4];
  #pragma unroll
  for (int i = 0; i < 4; ++i)
    #pragma unroll
    for (int j = 0; j < 4; ++j) acc[i][j] = f32x4{0.f, 0.f, 0.f, 0.f};

  // staging: wave wid covers rows [wid*32, wid*32+32), 4 passes x 8 rows.
  const int srow8 = lane >> 3;                       // row-within-pass == row&7
  const int scol = (((lane & 7) ^ srow8) << 3);      // swizzled source column
  const u16* aS = A + (long)(tm * 128 + (wid << 5) + srow8) * lda + scol;
  const u16* bS = Bt + (long)(tn * 128 + (wid << 5) + srow8) * ldb + scol;
  u16* aD = &As[wid * 2048];
  u16* bD = &Bs[wid * 2048];

  const int x7 = l15 & 7;
  const int cx0 = ((l4 ^ x7) << 3);                  // ks=0
  const int cx1 = (((l4 + 4) ^ x7) << 3);            // ks=1

  for (int k0 = 0; k0 < K; k0 += 64) {
    #pragma unroll
    for (int L = 0; L < 4; ++L) {
      gload16(aS + (long)(L * 8) * lda, aD + L * 512);
      gload16(bS + (long)(L * 8) * ldb, bD + L * 512);
    }
    __syncthreads();   // compiler drains vmcnt before barrier
    #pragma unroll
    for (int ks = 0; ks < 2; ++ks) {
      const int cx = ks ? cx1 : cx0;
      s16x8 af[4], bfr[4];
      #pragma unroll
      for (int i = 0; i < 4; ++i)
        af[i] = *(const s16x8*)&As[((wr << 6) + (i << 4) + l15) * 64 + cx];
      #pragma unroll
      for (int j = 0; j < 4; ++j)
        bfr[j] = *(const s16x8*)&Bs[((wc << 6) + (j << 4) + l15) * 64 + cx];
      #pragma unroll
      for (int i = 0; i < 4; ++i)
        #pragma unroll
        for (int j = 0; j < 4; ++j)
          acc[i][j] = __builtin_amdgcn_mfma_f32_16x16x32_bf16(af[i], bfr[j], acc[i][j], 0, 0, 0);
    }
    __syncthreads();
    aS += 64; bS += 64;
  }
  // all gload_lds drained -> smem reusable

  if (!(EPI & 8)) {
    u16 (*Cs)[128] = (u16(*)[128])smem;   // 64 x 128 bf16 = 16 KB
    #pragma unroll
    for (int p = 0; p < 2; ++p) {
      if (wr == p) {
        #pragma unroll
        for (int j = 0; j < 4; ++j) {
          const int c = (wc << 6) + (j << 4) + l15;
          const float bv = (EPI & 1) ? bias[tn * 128 + c] : 0.f;
          #pragma unroll
          for (int i = 0; i < 4; ++i) {
            const int lr = (i << 4) + (l4 << 2);
            #pragma unroll
            for (int r = 0; r < 4; ++r) {
              float v = acc[i][j][r] * scale + bv;
              if (EPI & 2) v = gelu_f(v);
              Cs[lr + r][c] = f2bf(v);
            }
          }
        }
      }
      __syncthreads();
      #pragma unroll
      for (int it = 0; it < 4; ++it) {
        const int row = (tid >> 4) + (it << 4);
        const int chunk = tid & 15;
        const long Gr = tm * 128 + (p << 6) + row;
        const int col0 = tn * 128 + (chunk << 3);
        s16x8 cv = *(s16x8*)&Cs[row][chunk << 3];
        if (EPI & 4) {
          const s16x8 rv = *(const s16x8*)&resid[Gr * ldc + col0];
          #pragma unroll
          for (int e = 0; e < 8; ++e)
            cv[e] = (short)f2bf(bf2f((u16)cv[e]) + bf2f((u16)rv[e]));
        }
        *(s16x8*)&C[Gr * ldc + col0] = cv;
      }
      if (p == 0) __syncthreads();
    }
  } else {
    u16 (*Ct)[136] = (u16(*)[136])smem;   // 64 x (128+8 pad) bf16
    #pragma unroll
    for (int p = 0; p < 2; ++p) {
      if (wc == p) {
        #pragma unroll
        for (int j = 0; j < 4; ++j) {
          const int lc = (j << 4) + l15;
          const float bv = (EPI & 1) ? bias[tn * 128 + (p << 6) + lc] : 0.f;
          #pragma unroll
          for (int i = 0; i < 4; ++i) {
            const int row_lo = (wr << 6) + (i << 4) + (l4 << 2);
            s16x4 pk;
            #pragma unroll
            for (int r = 0; r < 4; ++r) {
              float v = acc[i][j][r] * scale + bv;
              if (EPI & 2) v = gelu_f(v);
              pk[r] = (short)f2bf(v);
            }
            *(s16x4*)&Ct[lc][row_lo] = pk;
          }
        }
      }
      __syncthreads();
      #pragma unroll
      for (int it = 0; it < 4; ++it) {
        const int lc = (tid >> 4) + (it << 4);
        const int chunk = tid & 15;
        const long Gc = tn * 128 + (p << 6) + lc;
        const int col0 = tm * 128 + (chunk << 3);
        s16x8 cv = *(s16x8*)&Ct[lc][chunk << 3];
        *(s16x8*)&C[Gc * ldc + col0] = cv;
      }
      if (p == 0) __syncthreads();
    }
  }
}

// ---------------------------------------------------------------------------
// mega transpose: all six fp32 [K][N] weights -> bf16 [N][K], plus the
// q||k bias concat, in ONE launch.
// blocks [0,4096): q/k/v/o (each 1024 = 32x32), [4096,8192): int_w (128x32),
// [8192,12288): out_w (32x128), [12288,12296): qk_bias concat.
// ---------------------------------------------------------------------------
__global__ void mega_transpose_k(
    const float* __restrict__ q_w, const float* __restrict__ k_w,
    const float* __restrict__ v_w, const float* __restrict__ o_w,
    const float* __restrict__ int_w, const float* __restrict__ out_w,
    const float* __restrict__ q_bias, const float* __restrict__ k_bias,
    u16* __restrict__ qT, u16* __restrict__ kT, u16* __restrict__ vTw,
    u16* __restrict__ oT, u16* __restrict__ intT, u16* __restrict__ outT,
    float* __restrict__ qk_bias)
{
  const int id = blockIdx.x;
  const int t = threadIdx.x, tx = t & 31, ty = t >> 5;
  if (id >= 12288) {
    const int i = ((id - 12288) << 8) + t;
    qk_bias[i] = (i < Hc) ? q_bias[i] : k_bias[i - Hc];
    return;
  }
  const float* in; u16* out; int K, N, bx, by;
  if (id < 4096) {
    const int w = id >> 10, r = id & 1023;
    in  = (w == 0) ? q_w : (w == 1) ? k_w : (w == 2) ? v_w : o_w;
    out = (w == 0) ? qT  : (w == 1) ? kT  : (w == 2) ? vTw : oT;
    K = Hc; N = Hc; bx = r & 31; by = r >> 5;
  } else if (id < 8192) {
    const int r = id - 4096;
    in = int_w; out = intT; K = Hc; N = 4096; bx = r & 127; by = r >> 7;
  } else {
    const int r = id - 8192;
    in = out_w; out = outT; K = 4096; N = Hc; bx = r & 31; by = r >> 5;
  }
  __shared__ float tb[32][33];
  const int n0 = bx << 5, k0 = by << 5;
  #pragma unroll
  for (int i = 0; i < 32; i += 8)
    tb[ty + i][tx] = in[(long)(k0 + ty + i) * N + n0 + tx];
  __syncthreads();
  #pragma unroll
  for (int i = 0; i < 32; i += 8)
    out[(long)(n0 + ty + i) * K + k0 + tx] = f2bf(tb[tx][ty + i]);
}

// ---------------------------------------------------------------------------
// masked mean pool (deterministic 2-phase)
// ---------------------------------------------------------------------------
__global__ void pool_partial_k(const float* __restrict__ hs, const int* __restrict__ mask,
                               float* __restrict__ part) {
  const int h = (blockIdx.x << 8) + threadIdx.x;
  const int c = blockIdx.y, b = blockIdx.z;
  const int s0 = c * (Sc / 16);
  float acc = 0.f;
  for (int i = 0; i < Sc / 16; ++i) {
    const int s = s0 + i;
    acc += hs[((long)b * Sc + s) * Hc + h] * (float)mask[b * Sc + s];
  }
  part[((b << 4) + c) * Hc + h] = acc;
}

__global__ void pool_final_k(const float* __restrict__ part, const int* __restrict__ mask,
                             float* __restrict__ pooled) {
  const int b = blockIdx.x;
  __shared__ float red[4];
  __shared__ float denom_s;
  float d = 0.f;
  for (int i = threadIdx.x; i < Sc; i += 256) d += (float)mask[b * Sc + i];
  d = wred_sum(d);
  if ((threadIdx.x & 63) == 0) red[threadIdx.x >> 6] = d;
  __syncthreads();
  if (threadIdx.x == 0) denom_s = red[0] + red[1] + red[2] + red[3] + 1e-8f;
  __syncthreads();
  const float inv = 1.f / denom_s;
  for (int h = threadIdx.x; h < Hc; h += 256) {
    float s = 0.f;
    #pragma unroll
    for (int c = 0; c < 16; ++c) s += part[((b << 4) + c) * Hc + h];
    pooled[b * Hc + h] = s * inv;
  }
}

// ---------------------------------------------------------------------------
// split-K multi-row linear, stage 1: partial sums.
// ---------------------------------------------------------------------------
template<int R>
__global__ void mrow_part_k(const float* __restrict__ in, const float* __restrict__ W,
                            float* __restrict__ part, int K, int N) {
  const int t = threadIdx.x;
  const int jj = t & 31;
  const int j = (blockIdx.x << 5) + jj;
  const int ks = t >> 5;            // 0..7
  const int nchunk = gridDim.y;
  const int Kc = K / (nchunk << 3);
  const int k0 = ((blockIdx.y << 3) + ks) * Kc;
  float acc[R];
  #pragma unroll
  for (int r = 0; r < R; ++r) acc[r] = 0.f;
  for (int k = k0; k < k0 + Kc; ++k) {
    const float wv = W[(long)k * N + j];
    #pragma unroll
    for (int r = 0; r < R; ++r) acc[r] = fmaf(in[r * K + k], wv, acc[r]);
  }
  __shared__ float sm[8][R][32];
  #pragma unroll
  for (int r = 0; r < R; ++r) sm[ks][r][jj] = acc[r];
  __syncthreads();
  for (int idx = t; idx < R * 32; idx += 256) {
    const int r = idx >> 5, j2 = idx & 31;
    float s = 0.f;
    #pragma unroll
    for (int q = 0; q < 8; ++q) s += sm[q][r][j2];
    part[(long)(blockIdx.y * R + r) * N + (blockIdx.x << 5) + j2] = s;
  }
}

// stage 2: fixed-order reduce over chunks + bias + activation (deterministic)
template<bool GELU>
__global__ void mrow_reduce_k(const float* __restrict__ part, const float* __restrict__ bias,
                              float* __restrict__ out, int N, int R, int nchunk) {
  const int idx = (blockIdx.x << 8) + threadIdx.x;
  if (idx >= R * N) return;
  const int r = idx / N, j = idx - r * N;
  float s = 0.f;
  for (int c = 0; c < nchunk; ++c) s += part[(long)(c * R + r) * N + j];
  if (bias) s += bias[j];
  if (GELU) s = gelu_f(s);
  out[(long)r * N + j] = s;
}

// fused cp: reduce(8 chunks) + bias + gelu + LayerNorm -> hctx. grid = Bc.
__global__ void reduce_ln_cp_k(const float* __restrict__ part, const float* __restrict__ bias,
                               const float* __restrict__ g, const float* __restrict__ bb,
                               float* __restrict__ hctx) {
  const int b = blockIdx.x, t = threadIdx.x;
  __shared__ float red[4];
  float v[4]; float s = 0.f;
  #pragma unroll
  for (int i = 0; i < 4; ++i) {
    const int col = t + (i << 8);
    float a = bias[col];
    #pragma unroll
    for (int c = 0; c < 8; ++c) a += part[(long)((c << 2) + b) * Hc + col];
    v[i] = gelu_f(a);
    s += v[i];
  }
  s = wred_sum(s);
  if ((t & 63) == 0) red[t >> 6] = s;
  __syncthreads();
  const float mean = (red[0] + red[1] + red[2] + red[3]) * (1.f / Hc);
  float q = 0.f;
  #pragma unroll
  for (int i = 0; i < 4; ++i) { const float d2 = v[i] - mean; q += d2 * d2; }
  __syncthreads();
  q = wred_sum(q);
  if ((t & 63) == 0) red[t >> 6] = q;
  __syncthreads();
  const float var = (red[0] + red[1] + red[2] + red[3]) * (1.f / Hc);
  const float inv = rsqrtf(var + EPSc);
  #pragma unroll
  for (int i = 0; i < 4; ++i) {
    const int col = t + (i << 8);
    hctx[b * Hc + col] = (v[i] - mean) * inv * g[col] + bb[col];
  }
}

// fused: eph2 reduce (16 chunks, R=4, N=64) + gumbel argmax + build hwk.
// single block, 256 threads.
__global__ void zcode_fused_k(const float* __restrict__ part, const float* __restrict__ bias,
                              const float* __restrict__ gn, const float* __restrict__ cb,
                              const float* __restrict__ hctx, float* __restrict__ hwk) {
  const int t = threadIdx.x;
  __shared__ float zl[256];
  __shared__ int best[16];
  {
    const int r = t >> 6, j = t & 63;
    float s = bias[j];
    #pragma unroll
    for (int c = 0; c < 16; ++c) s += part[((c << 2) + r) * 64 + j];
    zl[t] = s;
  }
  __syncthreads();
  if (t < 16) {
    const int b = t >> 2, e = t & 3;
    int bi = 0; float bv = -3.4e38f;
    for (int c = 0; c < NCc; ++c) {
      const float val = (zl[(b << 6) + (e << 4) + c] + gn[((b << 2) + e) * NCc + c]) * (1.f / TAUc);
      if (val > bv) { bv = val; bi = c; }   // strict > == jnp.argmax first-max
    }
    best[t] = bi;
  }
  __syncthreads();
  for (int i = t; i < 16 * 1088; i += 256) {
    const int r = i / 1088, col = i - r * 1088;
    const int b = r >> 2;
    hwk[i] = (col < Hc) ? hctx[b * Hc + col] : cb[best[r] * CDc + (col - Hc)];
  }
}

// tv normalize + info gain + argmax select -> chosen
__global__ void select_k(const float* __restrict__ tv, const float* __restrict__ outc,
                         float* __restrict__ chosen) {
  const int b = blockIdx.x, t = threadIdx.x;   // 128 threads
  __shared__ float red[2];
  __shared__ float ig[NEc];
  __shared__ int bestIdx;
  const float x = tv[b * ODc + t];
  float ss = wred_sum(x * x);
  if ((t & 63) == 0) red[t >> 6] = ss;
  __syncthreads();
  float nrm = fmaxf(sqrtf(red[0] + red[1]), 1e-12f);
  const float tvn = x / nrm;
  __syncthreads();
  for (int ne = 0; ne < NEc; ++ne) {
    const float o = outc[(b * NEc + ne) * ODc + t];
    float a = wred_sum(o * o);
    float d2 = wred_sum(o * tvn);
    if ((t & 63) == 0) red[t >> 6] = a;
    __syncthreads();
    const float no = sqrtf(red[0] + red[1]);
    __syncthreads();
    if ((t & 63) == 0) red[t >> 6] = d2;
    __syncthreads();
    const float dd = red[0] + red[1];
    if (t == 0) ig[ne] = dd / fmaxf(no, 1e-12f) * (1.f / TEMPc);
    __syncthreads();
  }
  if (t == 0) {
    int bi = 0; float bvv = ig[0];
    for (int ne = 1; ne < NEc; ++ne) if (ig[ne] > bvv) { bvv = ig[ne]; bi = ne; }
    bestIdx = bi;
  }
  __syncthreads();
  chosen[b * ODc + t] = outc[(b * NEc + bestIdx) * ODc + t];
}

// fused = gamma*hidden + beta  (bf16 out)
__global__ void fuse_k(const float* __restrict__ hs, const float* __restrict__ gb,
                       u16* __restrict__ fused) {
  const long i = (((long)blockIdx.x << 8) + threadIdx.x) << 2;
  const int h = (int)(i & (Hc - 1));
  const int b = (int)(i >> 21);   // / (S*H) = 2^21
  const float4 xv = *(const float4*)(hs + i);
  const float* gp = gb + b * 2048;
  s16x4 pk = { (short)f2bf(fmaf(gp[h + 0], xv.x, gp[Hc + h + 0])),
               (short)f2bf(fmaf(gp[h + 1], xv.y, gp[Hc + h + 1])),
               (short)f2bf(fmaf(gp[h + 2], xv.z, gp[Hc + h + 2])),
               (short)f2bf(fmaf(gp[h + 3], xv.w, gp[Hc + h + 3])) };
  *(s16x4*)(fused + i) = pk;
}

// row softmax over 2048 bf16 scores (in-place), with attention mask.
// Vectorized: thread t owns contiguous cols [t*8, t*8+8) -> 16B load/store.
__global__ void softmax_k(u16* __restrict__ sc, const int* __restrict__ mask) {
  const long base = (long)blockIdx.x * Sc;
  const int b = blockIdx.x / Sc;
  const int t = threadIdx.x;
  __shared__ float red[4];
  s16x8 v8 = *(s16x8*)&sc[base + t * 8];
  const int4 m0 = *(const int4*)&mask[b * Sc + t * 8];
  const int4 m1 = *(const int4*)&mask[b * Sc + t * 8 + 4];
  float x[8];
  x[0] = (m0.x == 0) ? -3.0e38f : bf2f((u16)v8[0]);
  x[1] = (m0.y == 0) ? -3.0e38f : bf2f((u16)v8[1]);
  x[2] = (m0.z == 0) ? -3.0e38f : bf2f((u16)v8[2]);
  x[3] = (m0.w == 0) ? -3.0e38f : bf2f((u16)v8[3]);
  x[4] = (m1.x == 0) ? -3.0e38f : bf2f((u16)v8[4]);
  x[5] = (m1.y == 0) ? -3.0e38f : bf2f((u16)v8[5]);
  x[6] = (m1.z == 0) ? -3.0e38f : bf2f((u16)v8[6]);
  x[7] = (m1.w == 0) ? -3.0e38f : bf2f((u16)v8[7]);
  float mx = -3.0e38f;
  #pragma unroll
  for (int i = 0; i < 8; ++i) mx = fmaxf(mx, x[i]);
  mx = wred_max(mx);
  if ((t & 63) == 0) red[t >> 6] = mx;
  __syncthreads();
  mx = fmaxf(fmaxf(red[0], red[1]), fmaxf(red[2], red[3]));
  float sum = 0.f;
  #pragma unroll
  for (int i = 0; i < 8; ++i) { x[i] = __expf(x[i] - mx); sum += x[i]; }
  __syncthreads();
  sum = wred_sum(sum);
  if ((t & 63) == 0) red[t >> 6] = sum;
  __syncthreads();
  const float inv = 1.f / (red[0] + red[1] + red[2] + red[3]);
  s16x8 o8;
  #pragma unroll
  for (int i = 0; i < 8; ++i) o8[i] = (short)f2bf(x[i] * inv);
  *(s16x8*)&sc[base + t * 8] = o8;
}

// out = LN(ff + fused) * g + b   (fp32 out)
__global__ void final_ln_k(const u16* __restrict__ ff, const u16* __restrict__ fused,
                           const float* __restrict__ g, const float* __restrict__ b,
                           float* __restrict__ out) {
  const long base = (long)blockIdx.x * Hc;
  __shared__ float red[4];
  float v[4]; float s = 0.f;
  #pragma unroll
  for (int i = 0; i < 4; ++i) {
    const int col = threadIdx.x + (i << 8);
    v[i] = bf2f(ff[base + col]) + bf2f(fused[base + col]);
    s += v[i];
  }
  s = wred_sum(s);
  if ((threadIdx.x & 63) == 0) red[threadIdx.x >> 6] = s;
  __syncthreads();
  const float mean = (red[0] + red[1] + red[2] + red[3]) * (1.f / Hc);
  float q = 0.f;
  #pragma unroll
  for (int i = 0; i < 4; ++i) { const float d2 = v[i] - mean; q += d2 * d2; }
  __syncthreads();
  q = wred_sum(q);
  if ((threadIdx.x & 63) == 0) red[threadIdx.x >> 6] = q;
  __syncthreads();
  const float var = (red[0] + red[1] + red[2] + red[3]) * (1.f / Hc);
  const float inv = rsqrtf(var + EPSc);
  #pragma unroll
  for (int i = 0; i < 4; ++i) {
    const int col = threadIdx.x + (i << 8);
    out[base + col] = (v[i] - mean) * inv * g[col] + b[col];
  }
}

// ---------------------------------------------------------------------------
extern "C" void kernel_launch(void* const* d_in, const int* in_sizes, int n_in,
                              void* d_out, int out_size, void* d_ws, size_t ws_size,
                              hipStream_t stream) {
  const float* hs       = (const float*)d_in[0];
  const int*   amask    = (const int*)d_in[1];
  const float* gn       = (const float*)d_in[2];
  const float* cp_w     = (const float*)d_in[3];
  const float* cp_b     = (const float*)d_in[4];
  const float* cp_ln_g  = (const float*)d_in[5];
  const float* cp_ln_b  = (const float*)d_in[6];
  const float* eph_w1   = (const float*)d_in[7];
  const float* eph_b1   = (const float*)d_in[8];
  const float* eph_w2   = (const float*)d_in[9];
  const float* eph_b2   = (const float*)d_in[10];
  const float* codebook = (const float*)d_in[11];
  const float* wk_w1    = (const float*)d_in[12];
  const float* wk_b1    = (const float*)d_in[13];
  const float* wk_w2    = (const float*)d_in[14];
  const float* wk_b2    = (const float*)d_in[15];
  const float* tp_w     = (const float*)d_in[16];
  const float* film_w   = (const float*)d_in[17];
  const float* film_b   = (const float*)d_in[18];
  const float* q_w      = (const float*)d_in[19];
  const float* q_bias   = (const float*)d_in[20];
  const float* k_w      = (const float*)d_in[21];
  const float* k_bias   = (const float*)d_in[22];
  const float* v_w      = (const float*)d_in[23];
  const float* v_bias   = (const float*)d_in[24];
  const float* o_w      = (const float*)d_in[25];
  const float* o_bias   = (const float*)d_in[26];
  const float* int_w    = (const float*)d_in[27];
  const float* int_b    = (const float*)d_in[28];
  const float* out_w    = (const float*)d_in[29];
  const float* out_b    = (const float*)d_in[30];
  const float* ln_g     = (const float*)d_in[31];
  const float* ln_b     = (const float*)d_in[32];
  float* outp = (float*)d_out;

  char* w = (char*)d_ws;
  auto alloc = [&](size_t bytes) -> char* {
    char* p = w; w += (bytes + 255) & ~(size_t)255; return p;
  };
  float* part    = (float*)alloc((size_t)Bc * 16 * Hc * 4);
  float* pooled  = (float*)alloc((size_t)Bc * Hc * 4);
  float* hctx    = (float*)alloc((size_t)Bc * Hc * 4);
  float* t1      = (float*)alloc((size_t)Bc * Hc * 4);
  float* hwk     = (float*)alloc((size_t)16 * (Hc + CDc) * 4);
  float* wkt1    = (float*)alloc((size_t)16 * 2048 * 4);
  float* outcome = (float*)alloc((size_t)16 * ODc * 4);
  float* tvb     = (float*)alloc((size_t)Bc * ODc * 4);
  float* chosen  = (float*)alloc((size_t)Bc * ODc * 4);
  float* gb      = (float*)alloc((size_t)Bc * 2048 * 4);
  float* lin_part= (float*)alloc((size_t)1024 * 1024);   // 1 MB split-K partials
  float* qk_bias = (float*)alloc((size_t)2048 * 4);
  u16* qT    = (u16*)alloc((size_t)Hc * Hc * 2);         // qT,kT contiguous -> merged Bt
  u16* kT    = (u16*)alloc((size_t)Hc * Hc * 2);
  u16* vTw   = (u16*)alloc((size_t)Hc * Hc * 2);
  u16* oT    = (u16*)alloc((size_t)Hc * Hc * 2);
  u16* intT  = (u16*)alloc((size_t)Hc * 4096 * 2);
  u16* outT  = (u16*)alloc((size_t)Hc * 4096 * 2);
  u16* fused = (u16*)alloc((size_t)8192 * Hc * 2);
  u16* qkact = (u16*)alloc((size_t)8192 * 2048 * 2);     // q||k, ld 2048 (32 MB)
  u16* scores= (u16*)alloc((size_t)Bc * Sc * Sc * 2);    // 32 MB, right after qkact
  u16* vTact = (u16*)alloc((size_t)8192 * Hc * 2);
  u16* attn  = (u16*)alloc((size_t)8192 * Hc * 2);
  u16* h1    = (u16*)alloc((size_t)8192 * Hc * 2);
  u16* mid = qkact;  // FFN1 out [8192][4096] = qkact(32MB)+scores(32MB), both dead
  u16* ffo = attn;   // attn dead after o-proj

  if ((size_t)(w - (char*)d_ws) > ws_size) return;  // visible failure if ws too small

  mega_transpose_k<<<12296, 256, 0, stream>>>(q_w, k_w, v_w, o_w, int_w, out_w,
                                              q_bias, k_bias,
                                              qT, kT, vTw, oT, intT, outT, qk_bias);

  pool_partial_k<<<dim3(Hc / 256, 16, Bc), 256, 0, stream>>>(hs, amask, part);
  pool_final_k<<<Bc, 256, 0, stream>>>(part, amask, pooled);

  // h_ctx = LN(gelu(pooled @ cp_w + cp_b))
  mrow_part_k<4><<<dim3(32, 8), 256, 0, stream>>>(pooled, cp_w, lin_part, Hc, Hc);
  reduce_ln_cp_k<<<Bc, 256, 0, stream>>>(lin_part, cp_b, cp_ln_g, cp_ln_b, hctx);
  // t1 = gelu(hctx @ eph_w1 + b1)
  mrow_part_k<4><<<dim3(32, 8), 256, 0, stream>>>(hctx, eph_w1, lin_part, Hc, Hc);
  mrow_reduce_k<true><<<16, 256, 0, stream>>>(lin_part, eph_b1, t1, Hc, 4, 8);
  // zlog = t1 @ eph_w2 + b2 ; gumbel one-hot ; hwk = [hctx | codes]
  mrow_part_k<4><<<dim3(2, 16), 256, 0, stream>>>(t1, eph_w2, lin_part, Hc, 64);
  zcode_fused_k<<<1, 256, 0, stream>>>(lin_part, eph_b2, gn, codebook, hctx, hwk);
  // wkt1 = gelu(hwk @ wk_w1 + b1)   (16 x 1088 x 2048)
  mrow_part_k<16><<<dim3(64, 8), 256, 0, stream>>>(hwk, wk_w1, lin_part, Hc + CDc, 2048);
  mrow_reduce_k<true><<<128, 256, 0, stream>>>(lin_part, wk_b1, wkt1, 2048, 16, 8);
  // outcome = wkt1 @ wk_w2 + b2    (16 x 2048 x 128)
  mrow_part_k<16><<<dim3(4, 32), 256, 0, stream>>>(wkt1, wk_w2, lin_part, 2048, ODc);
  mrow_reduce_k<false><<<8, 256, 0, stream>>>(lin_part, wk_b2, outcome, ODc, 16, 32);
  // tv = hctx @ tp_w
  mrow_part_k<4><<<dim3(4, 8), 256, 0, stream>>>(hctx, tp_w, lin_part, Hc, ODc);
  mrow_reduce_k<false><<<2, 256, 0, stream>>>(lin_part, nullptr, tvb, ODc, 4, 8);
  select_k<<<Bc, 128, 0, stream>>>(tvb, outcome, chosen);
  // gb = gelu(chosen @ film_w + film_b)  (4 x 128 x 2048)
  mrow_part_k<4><<<dim3(64, 2), 256, 0, stream>>>(chosen, film_w, lin_part, ODc, 2048);
  mrow_reduce_k<true><<<32, 256, 0, stream>>>(lin_part, film_b, gb, 2048, 4, 2);
  fuse_k<<<8192, 256, 0, stream>>>(hs, gb, fused);

  // merged q||k projection: [8192][1024] @ [2048][1024]^T -> [8192][2048]
  gemm_bt<1><<<dim3(1024), 256, 0, stream>>>(fused, 0, Hc, qT, 0, Hc, qkact, 0, 2048,
                                             qk_bias, nullptr, 0, 1.f, 8192, 2048, Hc);
  // v written transposed ([H][B*S]) for the PV GEMM
  gemm_bt<9><<<dim3(512), 256, 0, stream>>>(fused, 0, Hc, vTw, 0, Hc, vTact, 0, 8192,
                                            v_bias, nullptr, 0, 1.f, 8192, Hc, Hc);
  // scores = q @ k^T / 32  (per batch; q = qkact cols 0-1023, k = cols 1024-2047)
  gemm_bt<0><<<dim3(256, 1, Bc), 256, 0, stream>>>(qkact, (long)Sc * 2048, 2048,
                                                   qkact + 1024, (long)Sc * 2048, 2048,
                                                   scores, (long)Sc * Sc, Sc,
                                                   nullptr, nullptr, 0, 0.03125f, Sc, Sc, Hc);
  softmax_k<<<Bc * Sc, 256, 0, stream>>>(scores, amask);
  // attn_out = P @ V   (Bt = vTact slice per batch)
  gemm_bt<0><<<dim3(128, 1, Bc), 256, 0, stream>>>(scores, (long)Sc * Sc, Sc,
                                                   vTact, (long)Sc, 8192,
                                                   attn, (long)Sc * Hc, Hc,
                                                   nullptr, nullptr, 0, 1.f, Sc, Hc, Sc);
  // o-proj + bias + residual(fused) -> h1
  gemm_bt<5><<<dim3(512), 256, 0, stream>>>(attn, 0, Hc, oT, 0, Hc, h1, 0, Hc,
                                            o_bias, fused, 0, 1.f, 8192, Hc, Hc);
  // FFN
  gemm_bt<3><<<dim3(2048), 256, 0, stream>>>(h1, 0, Hc, intT, 0, Hc, mid, 0, 4096,
                                             int_b, nullptr, 0, 1.f, 8192, 4096, Hc);
  gemm_bt<1><<<dim3(512), 256, 0, stream>>>(mid, 0, 4096, outT, 0, 4096, ffo, 0, Hc,
                                            out_b, nullptr, 0, 1.f, 8192, Hc, 4096);
  final_ln_k<<<Bc * Sc, 256, 0, stream>>>(ffo, fused, ln_g, ln_b, outp);
}

// Round 11
// 493.227 us; speedup vs baseline: 1.0049x; 1.0049x over previous
//
#include <hip/hip_runtime.h>
#include <math.h>

#define DEVI __device__ __forceinline__

typedef unsigned short u16;
typedef __attribute__((ext_vector_type(4))) float f32x4;
typedef __attribute__((ext_vector_type(8))) short s16x8;
typedef __attribute__((ext_vector_type(4))) short s16x4;

constexpr int Bc = 4, Sc = 2048, Hc = 1024;
constexpr int NEc = 4, NCc = 16, CDc = 64, ODc = 128;
constexpr float TAUc = 0.5f, TEMPc = 0.07f, EPSc = 1e-5f;

DEVI float gelu_f(float x) { return 0.5f * x * (1.0f + erff(x * 0.7071067811865476f)); }

DEVI float bf2f(u16 u) { union { unsigned int i; float f; } v; v.i = ((unsigned int)u) << 16; return v.f; }
DEVI u16 f2bf(float f) {
  union { float f; unsigned int i; } v; v.f = f;
  unsigned int u = v.i;
  unsigned int r = (u + 0x7fffu + ((u >> 16) & 1u)) >> 16;
  return (u16)r;
}

DEVI float wred_sum(float v) {
  #pragma unroll
  for (int o = 32; o > 0; o >>= 1) v += __shfl_down(v, o);
  return v;
}
DEVI float wred_max(float v) {
  #pragma unroll
  for (int o = 32; o > 0; o >>= 1) v = fmaxf(v, __shfl_down(v, o));
  return v;
}

DEVI void gload16(const void* g, void* l) {
  __builtin_amdgcn_global_load_lds((const __attribute__((address_space(1))) void*)g,
                                   (__attribute__((address_space(3))) void*)l, 16, 0, 0);
}

// ---------------------------------------------------------------------------
// bf16 GEMM, C = act(scale*(A @ Bt^T) + bias) (+ residual), 128x128 tile,
// BK=64, T2 XOR-swizzled LDS (linear gload_lds dest + XOR'd global source
// chunk + XOR'd ds_read slot). Coalesced LDS-staged epilogue.
// Tile order: XCD chunk (blockIdx%8) -> column-major band within the chunk's
// tm-rows (L2-fit; FFN1 FETCH 100->50MB, round 10).
// __launch_bounds__(256,4): 4 blocks/CU (16 waves) so other blocks' MFMA
// hides each block's vmcnt(0)+barrier drain (m114 overlap); LDS 4x32=128KB
// <=160, regs 64V+64A fit. (256,3) measured 37.8% occupancy, 33% MfmaUtil.
// EPI bits: 1=bias, 2=gelu, 4=residual add, 8=transposed store.
// NOTE (rounds 5-7): 256x256 8-phase "gemm8" compiled to VGPR=128 + full acc
// spill regardless of launch_bounds/waves_per_eu attrs -> abandoned.
// ---------------------------------------------------------------------------
template<int EPI>
__global__ __launch_bounds__(256, 4) void gemm_bt(
    const u16* __restrict__ A, long sAz, int lda,
    const u16* __restrict__ Bt, long sBz, int ldb,
    u16* __restrict__ C, long sCz, int ldc,
    const float* __restrict__ bias,
    const u16* __restrict__ resid, long sRz,
    float scale, int M, int N, int K)
{
  const int bz = blockIdx.z;
  A += (long)bz * sAz; Bt += (long)bz * sBz; C += (long)bz * sCz;
  if (EPI & 4) resid += (long)bz * sRz;

  const int nTn = N >> 7;
  int tm, tn;
  {
    const int nwg = gridDim.x;
    int bid = blockIdx.x;
    if ((nwg & 7) == 0 && ((nwg >> 3) % nTn) == 0) {
      // banded col-major within XCD chunk
      const int rows = (nwg >> 3) / nTn;      // tm-rows per chunk
      const int x = bid & 7, local = bid >> 3;
      tm = x * rows + (local % rows);
      tn = local / rows;
    } else {
      if ((nwg & 7) == 0) bid = ((bid & 7) * (nwg >> 3)) + (bid >> 3);
      tm = bid / nTn; tn = bid % nTn;
    }
  }
  const int tid = threadIdx.x;
  const int wid = tid >> 6, lane = tid & 63;
  const int wr = wid >> 1, wc = wid & 1;
  const int l15 = lane & 15, l4 = lane >> 4;

  __shared__ u16 smem[16384];         // 32 KB: As[128][64] + Bs[128][64]
  u16* As = smem;
  u16* Bs = smem + 8192;

  f32x4 acc[4][4];
  #pragma unroll
  for (int i = 0; i < 4; ++i)
    #pragma unroll
    for (int j = 0; j < 4; ++j) acc[i][j] = f32x4{0.f, 0.f, 0.f, 0.f};

  // staging: wave wid covers rows [wid*32, wid*32+32), 4 passes x 8 rows.
  const int srow8 = lane >> 3;                       // row-within-pass == row&7
  const int scol = (((lane & 7) ^ srow8) << 3);      // swizzled source column
  const u16* aS = A + (long)(tm * 128 + (wid << 5) + srow8) * lda + scol;
  const u16* bS = Bt + (long)(tn * 128 + (wid << 5) + srow8) * ldb + scol;
  u16* aD = &As[wid * 2048];
  u16* bD = &Bs[wid * 2048];

  const int x7 = l15 & 7;
  const int cx0 = ((l4 ^ x7) << 3);                  // ks=0
  const int cx1 = (((l4 + 4) ^ x7) << 3);            // ks=1

  for (int k0 = 0; k0 < K; k0 += 64) {
    #pragma unroll
    for (int L = 0; L < 4; ++L) {
      gload16(aS + (long)(L * 8) * lda, aD + L * 512);
      gload16(bS + (long)(L * 8) * ldb, bD + L * 512);
    }
    __syncthreads();   // compiler drains vmcnt before barrier
    #pragma unroll
    for (int ks = 0; ks < 2; ++ks) {
      const int cx = ks ? cx1 : cx0;
      s16x8 af[4], bfr[4];
      #pragma unroll
      for (int i = 0; i < 4; ++i)
        af[i] = *(const s16x8*)&As[((wr << 6) + (i << 4) + l15) * 64 + cx];
      #pragma unroll
      for (int j = 0; j < 4; ++j)
        bfr[j] = *(const s16x8*)&Bs[((wc << 6) + (j << 4) + l15) * 64 + cx];
      #pragma unroll
      for (int i = 0; i < 4; ++i)
        #pragma unroll
        for (int j = 0; j < 4; ++j)
          acc[i][j] = __builtin_amdgcn_mfma_f32_16x16x32_bf16(af[i], bfr[j], acc[i][j], 0, 0, 0);
    }
    __syncthreads();
    aS += 64; bS += 64;
  }
  // all gload_lds drained -> smem reusable

  if (!(EPI & 8)) {
    u16 (*Cs)[128] = (u16(*)[128])smem;   // 64 x 128 bf16 = 16 KB
    #pragma unroll
    for (int p = 0; p < 2; ++p) {
      if (wr == p) {
        #pragma unroll
        for (int j = 0; j < 4; ++j) {
          const int c = (wc << 6) + (j << 4) + l15;
          const float bv = (EPI & 1) ? bias[tn * 128 + c] : 0.f;
          #pragma unroll
          for (int i = 0; i < 4; ++i) {
            const int lr = (i << 4) + (l4 << 2);
            #pragma unroll
            for (int r = 0; r < 4; ++r) {
              float v = acc[i][j][r] * scale + bv;
              if (EPI & 2) v = gelu_f(v);
              Cs[lr + r][c] = f2bf(v);
            }
          }
        }
      }
      __syncthreads();
      #pragma unroll
      for (int it = 0; it < 4; ++it) {
        const int row = (tid >> 4) + (it << 4);
        const int chunk = tid & 15;
        const long Gr = tm * 128 + (p << 6) + row;
        const int col0 = tn * 128 + (chunk << 3);
        s16x8 cv = *(s16x8*)&Cs[row][chunk << 3];
        if (EPI & 4) {
          const s16x8 rv = *(const s16x8*)&resid[Gr * ldc + col0];
          #pragma unroll
          for (int e = 0; e < 8; ++e)
            cv[e] = (short)f2bf(bf2f((u16)cv[e]) + bf2f((u16)rv[e]));
        }
        *(s16x8*)&C[Gr * ldc + col0] = cv;
      }
      if (p == 0) __syncthreads();
    }
  } else {
    u16 (*Ct)[136] = (u16(*)[136])smem;   // 64 x (128+8 pad) bf16
    #pragma unroll
    for (int p = 0; p < 2; ++p) {
      if (wc == p) {
        #pragma unroll
        for (int j = 0; j < 4; ++j) {
          const int lc = (j << 4) + l15;
          const float bv = (EPI & 1) ? bias[tn * 128 + (p << 6) + lc] : 0.f;
          #pragma unroll
          for (int i = 0; i < 4; ++i) {
            const int row_lo = (wr << 6) + (i << 4) + (l4 << 2);
            s16x4 pk;
            #pragma unroll
            for (int r = 0; r < 4; ++r) {
              float v = acc[i][j][r] * scale + bv;
              if (EPI & 2) v = gelu_f(v);
              pk[r] = (short)f2bf(v);
            }
            *(s16x4*)&Ct[lc][row_lo] = pk;
          }
        }
      }
      __syncthreads();
      #pragma unroll
      for (int it = 0; it < 4; ++it) {
        const int lc = (tid >> 4) + (it << 4);
        const int chunk = tid & 15;
        const long Gc = tn * 128 + (p << 6) + lc;
        const int col0 = tm * 128 + (chunk << 3);
        s16x8 cv = *(s16x8*)&Ct[lc][chunk << 3];
        *(s16x8*)&C[Gc * ldc + col0] = cv;
      }
      if (p == 0) __syncthreads();
    }
  }
}

// ---------------------------------------------------------------------------
// mega transpose: all six fp32 [K][N] weights -> bf16 [N][K], plus the
// q||k bias concat, in ONE launch.
// ---------------------------------------------------------------------------
__global__ void mega_transpose_k(
    const float* __restrict__ q_w, const float* __restrict__ k_w,
    const float* __restrict__ v_w, const float* __restrict__ o_w,
    const float* __restrict__ int_w, const float* __restrict__ out_w,
    const float* __restrict__ q_bias, const float* __restrict__ k_bias,
    u16* __restrict__ qT, u16* __restrict__ kT, u16* __restrict__ vTw,
    u16* __restrict__ oT, u16* __restrict__ intT, u16* __restrict__ outT,
    float* __restrict__ qk_bias)
{
  const int id = blockIdx.x;
  const int t = threadIdx.x, tx = t & 31, ty = t >> 5;
  if (id >= 12288) {
    const int i = ((id - 12288) << 8) + t;
    qk_bias[i] = (i < Hc) ? q_bias[i] : k_bias[i - Hc];
    return;
  }
  const float* in; u16* out; int K, N, bx, by;
  if (id < 4096) {
    const int w = id >> 10, r = id & 1023;
    in  = (w == 0) ? q_w : (w == 1) ? k_w : (w == 2) ? v_w : o_w;
    out = (w == 0) ? qT  : (w == 1) ? kT  : (w == 2) ? vTw : oT;
    K = Hc; N = Hc; bx = r & 31; by = r >> 5;
  } else if (id < 8192) {
    const int r = id - 4096;
    in = int_w; out = intT; K = Hc; N = 4096; bx = r & 127; by = r >> 7;
  } else {
    const int r = id - 8192;
    in = out_w; out = outT; K = 4096; N = Hc; bx = r & 31; by = r >> 5;
  }
  __shared__ float tb[32][33];
  const int n0 = bx << 5, k0 = by << 5;
  #pragma unroll
  for (int i = 0; i < 32; i += 8)
    tb[ty + i][tx] = in[(long)(k0 + ty + i) * N + n0 + tx];
  __syncthreads();
  #pragma unroll
  for (int i = 0; i < 32; i += 8)
    out[(long)(n0 + ty + i) * K + k0 + tx] = f2bf(tb[tx][ty + i]);
}

// ---------------------------------------------------------------------------
// masked mean pool (deterministic 2-phase)
// ---------------------------------------------------------------------------
__global__ void pool_partial_k(const float* __restrict__ hs, const int* __restrict__ mask,
                               float* __restrict__ part) {
  const int h = (blockIdx.x << 8) + threadIdx.x;
  const int c = blockIdx.y, b = blockIdx.z;
  const int s0 = c * (Sc / 16);
  float acc = 0.f;
  for (int i = 0; i < Sc / 16; ++i) {
    const int s = s0 + i;
    acc += hs[((long)b * Sc + s) * Hc + h] * (float)mask[b * Sc + s];
  }
  part[((b << 4) + c) * Hc + h] = acc;
}

__global__ void pool_final_k(const float* __restrict__ part, const int* __restrict__ mask,
                             float* __restrict__ pooled) {
  const int b = blockIdx.x;
  __shared__ float red[4];
  __shared__ float denom_s;
  float d = 0.f;
  for (int i = threadIdx.x; i < Sc; i += 256) d += (float)mask[b * Sc + i];
  d = wred_sum(d);
  if ((threadIdx.x & 63) == 0) red[threadIdx.x >> 6] = d;
  __syncthreads();
  if (threadIdx.x == 0) denom_s = red[0] + red[1] + red[2] + red[3] + 1e-8f;
  __syncthreads();
  const float inv = 1.f / denom_s;
  for (int h = threadIdx.x; h < Hc; h += 256) {
    float s = 0.f;
    #pragma unroll
    for (int c = 0; c < 16; ++c) s += part[((b << 4) + c) * Hc + h];
    pooled[b * Hc + h] = s * inv;
  }
}

// ---------------------------------------------------------------------------
// split-K multi-row linear, stage 1: partial sums.
// ---------------------------------------------------------------------------
template<int R>
__global__ void mrow_part_k(const float* __restrict__ in, const float* __restrict__ W,
                            float* __restrict__ part, int K, int N) {
  const int t = threadIdx.x;
  const int jj = t & 31;
  const int j = (blockIdx.x << 5) + jj;
  const int ks = t >> 5;            // 0..7
  const int nchunk = gridDim.y;
  const int Kc = K / (nchunk << 3);
  const int k0 = ((blockIdx.y << 3) + ks) * Kc;
  float acc[R];
  #pragma unroll
  for (int r = 0; r < R; ++r) acc[r] = 0.f;
  for (int k = k0; k < k0 + Kc; ++k) {
    const float wv = W[(long)k * N + j];
    #pragma unroll
    for (int r = 0; r < R; ++r) acc[r] = fmaf(in[r * K + k], wv, acc[r]);
  }
  __shared__ float sm[8][R][32];
  #pragma unroll
  for (int r = 0; r < R; ++r) sm[ks][r][jj] = acc[r];
  __syncthreads();
  for (int idx = t; idx < R * 32; idx += 256) {
    const int r = idx >> 5, j2 = idx & 31;
    float s = 0.f;
    #pragma unroll
    for (int q = 0; q < 8; ++q) s += sm[q][r][j2];
    part[(long)(blockIdx.y * R + r) * N + (blockIdx.x << 5) + j2] = s;
  }
}

// stage 2: fixed-order reduce over chunks + bias + activation (deterministic)
template<bool GELU>
__global__ void mrow_reduce_k(const float* __restrict__ part, const float* __restrict__ bias,
                              float* __restrict__ out, int N, int R, int nchunk) {
  const int idx = (blockIdx.x << 8) + threadIdx.x;
  if (idx >= R * N) return;
  const int r = idx / N, j = idx - r * N;
  float s = 0.f;
  for (int c = 0; c < nchunk; ++c) s += part[(long)(c * R + r) * N + j];
  if (bias) s += bias[j];
  if (GELU) s = gelu_f(s);
  out[(long)r * N + j] = s;
}

// fused cp: reduce(8 chunks) + bias + gelu + LayerNorm -> hctx. grid = Bc.
__global__ void reduce_ln_cp_k(const float* __restrict__ part, const float* __restrict__ bias,
                               const float* __restrict__ g, const float* __restrict__ bb,
                               float* __restrict__ hctx) {
  const int b = blockIdx.x, t = threadIdx.x;
  __shared__ float red[4];
  float v[4]; float s = 0.f;
  #pragma unroll
  for (int i = 0; i < 4; ++i) {
    const int col = t + (i << 8);
    float a = bias[col];
    #pragma unroll
    for (int c = 0; c < 8; ++c) a += part[(long)((c << 2) + b) * Hc + col];
    v[i] = gelu_f(a);
    s += v[i];
  }
  s = wred_sum(s);
  if ((t & 63) == 0) red[t >> 6] = s;
  __syncthreads();
  const float mean = (red[0] + red[1] + red[2] + red[3]) * (1.f / Hc);
  float q = 0.f;
  #pragma unroll
  for (int i = 0; i < 4; ++i) { const float d2 = v[i] - mean; q += d2 * d2; }
  __syncthreads();
  q = wred_sum(q);
  if ((t & 63) == 0) red[t >> 6] = q;
  __syncthreads();
  const float var = (red[0] + red[1] + red[2] + red[3]) * (1.f / Hc);
  const float inv = rsqrtf(var + EPSc);
  #pragma unroll
  for (int i = 0; i < 4; ++i) {
    const int col = t + (i << 8);
    hctx[b * Hc + col] = (v[i] - mean) * inv * g[col] + bb[col];
  }
}

// fused: eph2 reduce (16 chunks, R=4, N=64) + gumbel argmax + build hwk.
// single block, 256 threads.
__global__ void zcode_fused_k(const float* __restrict__ part, const float* __restrict__ bias,
                              const float* __restrict__ gn, const float* __restrict__ cb,
                              const float* __restrict__ hctx, float* __restrict__ hwk) {
  const int t = threadIdx.x;
  __shared__ float zl[256];
  __shared__ int best[16];
  {
    const int r = t >> 6, j = t & 63;
    float s = bias[j];
    #pragma unroll
    for (int c = 0; c < 16; ++c) s += part[((c << 2) + r) * 64 + j];
    zl[t] = s;
  }
  __syncthreads();
  if (t < 16) {
    const int b = t >> 2, e = t & 3;
    int bi = 0; float bv = -3.4e38f;
    for (int c = 0; c < NCc; ++c) {
      const float val = (zl[(b << 6) + (e << 4) + c] + gn[((b << 2) + e) * NCc + c]) * (1.f / TAUc);
      if (val > bv) { bv = val; bi = c; }   // strict > == jnp.argmax first-max
    }
    best[t] = bi;
  }
  __syncthreads();
  for (int i = t; i < 16 * 1088; i += 256) {
    const int r = i / 1088, col = i - r * 1088;
    const int b = r >> 2;
    hwk[i] = (col < Hc) ? hctx[b * Hc + col] : cb[best[r] * CDc + (col - Hc)];
  }
}

// tv normalize + info gain + argmax select -> chosen
__global__ void select_k(const float* __restrict__ tv, const float* __restrict__ outc,
                         float* __restrict__ chosen) {
  const int b = blockIdx.x, t = threadIdx.x;   // 128 threads
  __shared__ float red[2];
  __shared__ float ig[NEc];
  __shared__ int bestIdx;
  const float x = tv[b * ODc + t];
  float ss = wred_sum(x * x);
  if ((t & 63) == 0) red[t >> 6] = ss;
  __syncthreads();
  float nrm = fmaxf(sqrtf(red[0] + red[1]), 1e-12f);
  const float tvn = x / nrm;
  __syncthreads();
  for (int ne = 0; ne < NEc; ++ne) {
    const float o = outc[(b * NEc + ne) * ODc + t];
    float a = wred_sum(o * o);
    float d2 = wred_sum(o * tvn);
    if ((t & 63) == 0) red[t >> 6] = a;
    __syncthreads();
    const float no = sqrtf(red[0] + red[1]);
    __syncthreads();
    if ((t & 63) == 0) red[t >> 6] = d2;
    __syncthreads();
    const float dd = red[0] + red[1];
    if (t == 0) ig[ne] = dd / fmaxf(no, 1e-12f) * (1.f / TEMPc);
    __syncthreads();
  }
  if (t == 0) {
    int bi = 0; float bvv = ig[0];
    for (int ne = 1; ne < NEc; ++ne) if (ig[ne] > bvv) { bvv = ig[ne]; bi = ne; }
    bestIdx = bi;
  }
  __syncthreads();
  chosen[b * ODc + t] = outc[(b * NEc + bestIdx) * ODc + t];
}

// fused = gamma*hidden + beta  (bf16 out)
__global__ void fuse_k(const float* __restrict__ hs, const float* __restrict__ gb,
                       u16* __restrict__ fused) {
  const long i = (((long)blockIdx.x << 8) + threadIdx.x) << 2;
  const int h = (int)(i & (Hc - 1));
  const int b = (int)(i >> 21);   // / (S*H) = 2^21
  const float4 xv = *(const float4*)(hs + i);
  const float* gp = gb + b * 2048;
  s16x4 pk = { (short)f2bf(fmaf(gp[h + 0], xv.x, gp[Hc + h + 0])),
               (short)f2bf(fmaf(gp[h + 1], xv.y, gp[Hc + h + 1])),
               (short)f2bf(fmaf(gp[h + 2], xv.z, gp[Hc + h + 2])),
               (short)f2bf(fmaf(gp[h + 3], xv.w, gp[Hc + h + 3])) };
  *(s16x4*)(fused + i) = pk;
}

// row softmax over 2048 bf16 scores (in-place), with attention mask.
// Vectorized: thread t owns contiguous cols [t*8, t*8+8) -> 16B load/store.
__global__ void softmax_k(u16* __restrict__ sc, const int* __restrict__ mask) {
  const long base = (long)blockIdx.x * Sc;
  const int b = blockIdx.x / Sc;
  const int t = threadIdx.x;
  __shared__ float red[4];
  s16x8 v8 = *(s16x8*)&sc[base + t * 8];
  const int4 m0 = *(const int4*)&mask[b * Sc + t * 8];
  const int4 m1 = *(const int4*)&mask[b * Sc + t * 8 + 4];
  float x[8];
  x[0] = (m0.x == 0) ? -3.0e38f : bf2f((u16)v8[0]);
  x[1] = (m0.y == 0) ? -3.0e38f : bf2f((u16)v8[1]);
  x[2] = (m0.z == 0) ? -3.0e38f : bf2f((u16)v8[2]);
  x[3] = (m0.w == 0) ? -3.0e38f : bf2f((u16)v8[3]);
  x[4] = (m1.x == 0) ? -3.0e38f : bf2f((u16)v8[4]);
  x[5] = (m1.y == 0) ? -3.0e38f : bf2f((u16)v8[5]);
  x[6] = (m1.z == 0) ? -3.0e38f : bf2f((u16)v8[6]);
  x[7] = (m1.w == 0) ? -3.0e38f : bf2f((u16)v8[7]);
  float mx = -3.0e38f;
  #pragma unroll
  for (int i = 0; i < 8; ++i) mx = fmaxf(mx, x[i]);
  mx = wred_max(mx);
  if ((t & 63) == 0) red[t >> 6] = mx;
  __syncthreads();
  mx = fmaxf(fmaxf(red[0], red[1]), fmaxf(red[2], red[3]));
  float sum = 0.f;
  #pragma unroll
  for (int i = 0; i < 8; ++i) { x[i] = __expf(x[i] - mx); sum += x[i]; }
  __syncthreads();
  sum = wred_sum(sum);
  if ((t & 63) == 0) red[t >> 6] = sum;
  __syncthreads();
  const float inv = 1.f / (red[0] + red[1] + red[2] + red[3]);
  s16x8 o8;
  #pragma unroll
  for (int i = 0; i < 8; ++i) o8[i] = (short)f2bf(x[i] * inv);
  *(s16x8*)&sc[base + t * 8] = o8;
}

// out = LN(ff + fused) * g + b (fp32 out). Vectorized: thread t owns 4
// contiguous cols [t*4, t*4+4) -> 8B bf16 loads, 16B fp32 store.
__global__ void final_ln_k(const u16* __restrict__ ff, const u16* __restrict__ fused,
                           const float* __restrict__ g, const float* __restrict__ b,
                           float* __restrict__ out) {
  const long base = (long)blockIdx.x * Hc;
  const int t = threadIdx.x;
  __shared__ float red[4];
  const s16x4 f4 = *(const s16x4*)&ff[base + t * 4];
  const s16x4 u4 = *(const s16x4*)&fused[base + t * 4];
  float v[4]; float s = 0.f;
  #pragma unroll
  for (int i = 0; i < 4; ++i) {
    v[i] = bf2f((u16)f4[i]) + bf2f((u16)u4[i]);
    s += v[i];
  }
  s = wred_sum(s);
  if ((t & 63) == 0) red[t >> 6] = s;
  __syncthreads();
  const float mean = (red[0] + red[1] + red[2] + red[3]) * (1.f / Hc);
  float q = 0.f;
  #pragma unroll
  for (int i = 0; i < 4; ++i) { const float d2 = v[i] - mean; q += d2 * d2; }
  __syncthreads();
  q = wred_sum(q);
  if ((t & 63) == 0) red[t >> 6] = q;
  __syncthreads();
  const float var = (red[0] + red[1] + red[2] + red[3]) * (1.f / Hc);
  const float inv = rsqrtf(var + EPSc);
  const float4 g4 = *(const float4*)&g[t * 4];
  const float4 b4 = *(const float4*)&b[t * 4];
  float4 o4;
  o4.x = (v[0] - mean) * inv * g4.x + b4.x;
  o4.y = (v[1] - mean) * inv * g4.y + b4.y;
  o4.z = (v[2] - mean) * inv * g4.z + b4.z;
  o4.w = (v[3] - mean) * inv * g4.w + b4.w;
  *(float4*)&out[base + t * 4] = o4;
}

// ---------------------------------------------------------------------------
extern "C" void kernel_launch(void* const* d_in, const int* in_sizes, int n_in,
                              void* d_out, int out_size, void* d_ws, size_t ws_size,
                              hipStream_t stream) {
  const float* hs       = (const float*)d_in[0];
  const int*   amask    = (const int*)d_in[1];
  const float* gn       = (const float*)d_in[2];
  const float* cp_w     = (const float*)d_in[3];
  const float* cp_b     = (const float*)d_in[4];
  const float* cp_ln_g  = (const float*)d_in[5];
  const float* cp_ln_b  = (const float*)d_in[6];
  const float* eph_w1   = (const float*)d_in[7];
  const float* eph_b1   = (const float*)d_in[8];
  const float* eph_w2   = (const float*)d_in[9];
  const float* eph_b2   = (const float*)d_in[10];
  const float* codebook = (const float*)d_in[11];
  const float* wk_w1    = (const float*)d_in[12];
  const float* wk_b1    = (const float*)d_in[13];
  const float* wk_w2    = (const float*)d_in[14];
  const float* wk_b2    = (const float*)d_in[15];
  const float* tp_w     = (const float*)d_in[16];
  const float* film_w   = (const float*)d_in[17];
  const float* film_b   = (const float*)d_in[18];
  const float* q_w      = (const float*)d_in[19];
  const float* q_bias   = (const float*)d_in[20];
  const float* k_w      = (const float*)d_in[21];
  const float* k_bias   = (const float*)d_in[22];
  const float* v_w      = (const float*)d_in[23];
  const float* v_bias   = (const float*)d_in[24];
  const float* o_w      = (const float*)d_in[25];
  const float* o_bias   = (const float*)d_in[26];
  const float* int_w    = (const float*)d_in[27];
  const float* int_b    = (const float*)d_in[28];
  const float* out_w    = (const float*)d_in[29];
  const float* out_b    = (const float*)d_in[30];
  const float* ln_g     = (const float*)d_in[31];
  const float* ln_b     = (const float*)d_in[32];
  float* outp = (float*)d_out;

  char* w = (char*)d_ws;
  auto alloc = [&](size_t bytes) -> char* {
    char* p = w; w += (bytes + 255) & ~(size_t)255; return p;
  };
  float* part    = (float*)alloc((size_t)Bc * 16 * Hc * 4);
  float* pooled  = (float*)alloc((size_t)Bc * Hc * 4);
  float* hctx    = (float*)alloc((size_t)Bc * Hc * 4);
  float* t1      = (float*)alloc((size_t)Bc * Hc * 4);
  float* hwk     = (float*)alloc((size_t)16 * (Hc + CDc) * 4);
  float* wkt1    = (float*)alloc((size_t)16 * 2048 * 4);
  float* outcome = (float*)alloc((size_t)16 * ODc * 4);
  float* tvb     = (float*)alloc((size_t)Bc * ODc * 4);
  float* chosen  = (float*)alloc((size_t)Bc * ODc * 4);
  float* gb      = (float*)alloc((size_t)Bc * 2048 * 4);
  float* lin_part= (float*)alloc((size_t)1024 * 1024);   // 1 MB split-K partials
  float* qk_bias = (float*)alloc((size_t)2048 * 4);
  u16* qT    = (u16*)alloc((size_t)Hc * Hc * 2);         // qT,kT contiguous -> merged Bt
  u16* kT    = (u16*)alloc((size_t)Hc * Hc * 2);
  u16* vTw   = (u16*)alloc((size_t)Hc * Hc * 2);
  u16* oT    = (u16*)alloc((size_t)Hc * Hc * 2);
  u16* intT  = (u16*)alloc((size_t)Hc * 4096 * 2);
  u16* outT  = (u16*)alloc((size_t)Hc * 4096 * 2);
  u16* fused = (u16*)alloc((size_t)8192 * Hc * 2);
  u16* qkact = (u16*)alloc((size_t)8192 * 2048 * 2);     // q||k, ld 2048 (32 MB)
  u16* scores= (u16*)alloc((size_t)Bc * Sc * Sc * 2);    // 32 MB, right after qkact
  u16* vTact = (u16*)alloc((size_t)8192 * Hc * 2);
  u16* attn  = (u16*)alloc((size_t)8192 * Hc * 2);
  u16* h1    = (u16*)alloc((size_t)8192 * Hc * 2);
  u16* mid = qkact;  // FFN1 out [8192][4096] = qkact(32MB)+scores(32MB), both dead
  u16* ffo = attn;   // attn dead after o-proj

  if ((size_t)(w - (char*)d_ws) > ws_size) return;  // visible failure if ws too small

  mega_transpose_k<<<12296, 256, 0, stream>>>(q_w, k_w, v_w, o_w, int_w, out_w,
                                              q_bias, k_bias,
                                              qT, kT, vTw, oT, intT, outT, qk_bias);

  pool_partial_k<<<dim3(Hc / 256, 16, Bc), 256, 0, stream>>>(hs, amask, part);
  pool_final_k<<<Bc, 256, 0, stream>>>(part, amask, pooled);

  // h_ctx = LN(gelu(pooled @ cp_w + cp_b))
  mrow_part_k<4><<<dim3(32, 8), 256, 0, stream>>>(pooled, cp_w, lin_part, Hc, Hc);
  reduce_ln_cp_k<<<Bc, 256, 0, stream>>>(lin_part, cp_b, cp_ln_g, cp_ln_b, hctx);
  // t1 = gelu(hctx @ eph_w1 + b1)
  mrow_part_k<4><<<dim3(32, 8), 256, 0, stream>>>(hctx, eph_w1, lin_part, Hc, Hc);
  mrow_reduce_k<true><<<16, 256, 0, stream>>>(lin_part, eph_b1, t1, Hc, 4, 8);
  // zlog = t1 @ eph_w2 + b2 ; gumbel one-hot ; hwk = [hctx | codes]
  mrow_part_k<4><<<dim3(2, 16), 256, 0, stream>>>(t1, eph_w2, lin_part, Hc, 64);
  zcode_fused_k<<<1, 256, 0, stream>>>(lin_part, eph_b2, gn, codebook, hctx, hwk);
  // wkt1 = gelu(hwk @ wk_w1 + b1)   (16 x 1088 x 2048)
  mrow_part_k<16><<<dim3(64, 8), 256, 0, stream>>>(hwk, wk_w1, lin_part, Hc + CDc, 2048);
  mrow_reduce_k<true><<<128, 256, 0, stream>>>(lin_part, wk_b1, wkt1, 2048, 16, 8);
  // outcome = wkt1 @ wk_w2 + b2    (16 x 2048 x 128)
  mrow_part_k<16><<<dim3(4, 32), 256, 0, stream>>>(wkt1, wk_w2, lin_part, 2048, ODc);
  mrow_reduce_k<false><<<8, 256, 0, stream>>>(lin_part, wk_b2, outcome, ODc, 16, 32);
  // tv = hctx @ tp_w
  mrow_part_k<4><<<dim3(4, 8), 256, 0, stream>>>(hctx, tp_w, lin_part, Hc, ODc);
  mrow_reduce_k<false><<<2, 256, 0, stream>>>(lin_part, nullptr, tvb, ODc, 4, 8);
  select_k<<<Bc, 128, 0, stream>>>(tvb, outcome, chosen);
  // gb = gelu(chosen @ film_w + film_b)  (4 x 128 x 2048)
  mrow_part_k<4><<<dim3(64, 2), 256, 0, stream>>>(chosen, film_w, lin_part, ODc, 2048);
  mrow_reduce_k<true><<<32, 256, 0, stream>>>(lin_part, film_b, gb, 2048, 4, 2);
  fuse_k<<<8192, 256, 0, stream>>>(hs, gb, fused);

  // merged q||k projection: [8192][1024] @ [2048][1024]^T -> [8192][2048]
  gemm_bt<1><<<dim3(1024), 256, 0, stream>>>(fused, 0, Hc, qT, 0, Hc, qkact, 0, 2048,
                                             qk_bias, nullptr, 0, 1.f, 8192, 2048, Hc);
  // v written transposed ([H][B*S]) for the PV GEMM
  gemm_bt<9><<<dim3(512), 256, 0, stream>>>(fused, 0, Hc, vTw, 0, Hc, vTact, 0, 8192,
                                            v_bias, nullptr, 0, 1.f, 8192, Hc, Hc);
  // scores = q @ k^T / 32  (per batch; q = qkact cols 0-1023, k = cols 1024-2047)
  gemm_bt<0><<<dim3(256, 1, Bc), 256, 0, stream>>>(qkact, (long)Sc * 2048, 2048,
                                                   qkact + 1024, (long)Sc * 2048, 2048,
                                                   scores, (long)Sc * Sc, Sc,
                                                   nullptr, nullptr, 0, 0.03125f, Sc, Sc, Hc);
  softmax_k<<<Bc * Sc, 256, 0, stream>>>(scores, amask);
  // attn_out = P @ V   (Bt = vTact slice per batch)
  gemm_bt<0><<<dim3(128, 1, Bc), 256, 0, stream>>>(scores, (long)Sc * Sc, Sc,
                                                   vTact, (long)Sc, 8192,
                                                   attn, (long)Sc * Hc, Hc,
                                                   nullptr, nullptr, 0, 1.f, Sc, Hc, Sc);
  // o-proj + bias + residual(fused) -> h1
  gemm_bt<5><<<dim3(512), 256, 0, stream>>>(attn, 0, Hc, oT, 0, Hc, h1, 0, Hc,
                                            o_bias, fused, 0, 1.f, 8192, Hc, Hc);
  // FFN
  gemm_bt<3><<<dim3(2048), 256, 0, stream>>>(h1, 0, Hc, intT, 0, Hc, mid, 0, 4096,
                                             int_b, nullptr, 0, 1.f, 8192, 4096, Hc);
  gemm_bt<1><<<dim3(512), 256, 0, stream>>>(mid, 0, 4096, outT, 0, 4096, ffo, 0, Hc,
                                            out_b, nullptr, 0, 1.f, 8192, Hc, 4096);
  final_ln_k<<<Bc * Sc, 256, 0, stream>>>(ffo, fused, ln_g, ln_b, outp);
}